// Round 1
// baseline (1024.111 us; speedup 1.0000x reference)
//
#include <hip/hip_runtime.h>
#include <math.h>

#define NQ      16384
#define NKV     32768
#define CIN     64
#define NF      128
#define NOFF    27
#define BATCH   8
#define SQ      2048
#define SKV     4096
#define BN_EPS  1e-4f

// ---------------------------------------------------------------------------
// Kernel 1: p1 submanifold conv:  x_dec[n][f] = sum_{ko,c} xfeat[nbr[n][ko]][c] * Wp1[ko][c][f]
// Treated as gathered GEMM: [64 pts x 1728] @ [1728 x 128], K-chunked by 64 (one offset ko).
// grid = NQ/64, block = 256
// ---------------------------------------------------------------------------
__global__ __launch_bounds__(256) void p1conv_kernel(
    const float* __restrict__ xfeat, const int* __restrict__ nbr,
    const float* __restrict__ Wp1, float* __restrict__ out)
{
    __shared__ float As[64][68];    // pts x chan (pad 4: 2-way max)
    __shared__ float Bs[64][132];   // chan x feat (pad 4)
    const int t    = threadIdx.x;
    const int base = blockIdx.x * 64;
    const int ty   = t >> 4;        // 0..15 -> rows ty*4+i
    const int tx   = t & 15;        // feats tx*4+u and 64+tx*4+u
    const int pl   = t >> 2;        // A-load point
    const int c0   = (t & 3) * 16;  // A-load channel start

    float4 acc[4][2];
    #pragma unroll
    for (int i = 0; i < 4; i++) {
        acc[i][0] = make_float4(0.f, 0.f, 0.f, 0.f);
        acc[i][1] = make_float4(0.f, 0.f, 0.f, 0.f);
    }

    for (int ko = 0; ko < NOFF; ko++) {
        __syncthreads();
        // gather A tile: 64 pts x 64 chans
        int idx = nbr[(size_t)(base + pl) * NOFF + ko];
        const float* srcA = xfeat + (size_t)idx * CIN + c0;
        float4 a0 = *(const float4*)(srcA + 0);
        float4 a1 = *(const float4*)(srcA + 4);
        float4 a2 = *(const float4*)(srcA + 8);
        float4 a3 = *(const float4*)(srcA + 12);
        // load B tile: Wp1[ko] 64x128
        const float* srcB = Wp1 + (size_t)ko * CIN * NF;
        float4 bv[8];
        #pragma unroll
        for (int k = 0; k < 8; k++) {
            int fi = k * 256 + t;
            bv[k] = *(const float4*)(srcB + fi * 4);
        }
        *(float4*)&As[pl][c0 + 0]  = a0;
        *(float4*)&As[pl][c0 + 4]  = a1;
        *(float4*)&As[pl][c0 + 8]  = a2;
        *(float4*)&As[pl][c0 + 12] = a3;
        #pragma unroll
        for (int k = 0; k < 8; k++) {
            int fi = k * 256 + t;
            int r  = fi >> 5;
            int cc = (fi & 31) * 4;
            *(float4*)&Bs[r][cc] = bv[k];
        }
        __syncthreads();
        #pragma unroll 4
        for (int c = 0; c < 64; c++) {
            float a[4];
            #pragma unroll
            for (int i = 0; i < 4; i++) a[i] = As[ty * 4 + i][c];
            float4 b0 = *(float4*)&Bs[c][tx * 4];
            float4 b1 = *(float4*)&Bs[c][tx * 4 + 64];
            #pragma unroll
            for (int i = 0; i < 4; i++) {
                acc[i][0].x += a[i] * b0.x; acc[i][0].y += a[i] * b0.y;
                acc[i][0].z += a[i] * b0.z; acc[i][0].w += a[i] * b0.w;
                acc[i][1].x += a[i] * b1.x; acc[i][1].y += a[i] * b1.y;
                acc[i][1].z += a[i] * b1.z; acc[i][1].w += a[i] * b1.w;
            }
        }
    }
    #pragma unroll
    for (int i = 0; i < 4; i++) {
        float* dst = out + (size_t)(base + ty * 4 + i) * NF;
        *(float4*)(dst + tx * 4)      = acc[i][0];
        *(float4*)(dst + tx * 4 + 64) = acc[i][1];
    }
}

// ---------------------------------------------------------------------------
// Kernel 2: generic C[M,128] = A[M,K] @ W[K,128], K in {64,128}
// grid = M/64, block = 256
// ---------------------------------------------------------------------------
__global__ __launch_bounds__(256) void gemm_nf128(
    const float* __restrict__ A, const float* __restrict__ W,
    float* __restrict__ C, int K)
{
    __shared__ float As[64][68];
    __shared__ float Bs[64][132];
    const int t    = threadIdx.x;
    const int base = blockIdx.x * 64;
    const int ty   = t >> 4;
    const int tx   = t & 15;
    const int pl   = t >> 2;
    const int c0   = (t & 3) * 16;

    float4 acc[4][2];
    #pragma unroll
    for (int i = 0; i < 4; i++) {
        acc[i][0] = make_float4(0.f, 0.f, 0.f, 0.f);
        acc[i][1] = make_float4(0.f, 0.f, 0.f, 0.f);
    }

    for (int k0 = 0; k0 < K; k0 += 64) {
        __syncthreads();
        const float* srcA = A + (size_t)(base + pl) * K + k0 + c0;
        float4 a0 = *(const float4*)(srcA + 0);
        float4 a1 = *(const float4*)(srcA + 4);
        float4 a2 = *(const float4*)(srcA + 8);
        float4 a3 = *(const float4*)(srcA + 12);
        float4 bv[8];
        #pragma unroll
        for (int k = 0; k < 8; k++) {
            int fi = k * 256 + t;
            int r  = fi >> 5;
            int cc = (fi & 31) * 4;
            bv[k] = *(const float4*)(W + (size_t)(k0 + r) * NF + cc);
        }
        *(float4*)&As[pl][c0 + 0]  = a0;
        *(float4*)&As[pl][c0 + 4]  = a1;
        *(float4*)&As[pl][c0 + 8]  = a2;
        *(float4*)&As[pl][c0 + 12] = a3;
        #pragma unroll
        for (int k = 0; k < 8; k++) {
            int fi = k * 256 + t;
            int r  = fi >> 5;
            int cc = (fi & 31) * 4;
            *(float4*)&Bs[r][cc] = bv[k];
        }
        __syncthreads();
        #pragma unroll 4
        for (int c = 0; c < 64; c++) {
            float a[4];
            #pragma unroll
            for (int i = 0; i < 4; i++) a[i] = As[ty * 4 + i][c];
            float4 b0 = *(float4*)&Bs[c][tx * 4];
            float4 b1 = *(float4*)&Bs[c][tx * 4 + 64];
            #pragma unroll
            for (int i = 0; i < 4; i++) {
                acc[i][0].x += a[i] * b0.x; acc[i][0].y += a[i] * b0.y;
                acc[i][0].z += a[i] * b0.z; acc[i][0].w += a[i] * b0.w;
                acc[i][1].x += a[i] * b1.x; acc[i][1].y += a[i] * b1.y;
                acc[i][1].z += a[i] * b1.z; acc[i][1].w += a[i] * b1.w;
            }
        }
    }
    #pragma unroll
    for (int i = 0; i < 4; i++) {
        float* dst = C + (size_t)(base + ty * 4 + i) * NF;
        *(float4*)(dst + tx * 4)      = acc[i][0];
        *(float4*)(dst + tx * 4 + 64) = acc[i][1];
    }
}

// ---------------------------------------------------------------------------
// Kernel 3: flash attention per batch; no 1/sqrt(d) scale (matches reference).
// grid = (SQ/64, BATCH), block = 256. 64 q-rows per block, KV tiles of 64.
// ---------------------------------------------------------------------------
__global__ __launch_bounds__(256) void attn_kernel(
    const float* __restrict__ Q, const float* __restrict__ Km,
    const float* __restrict__ Vm, float* __restrict__ O)
{
    __shared__ float qs[64][132];
    __shared__ float ks[64][132];
    __shared__ float vs[64][132];
    __shared__ float Ss[64][68];
    __shared__ float mrow[64], lrow[64], arow[64];

    const int t  = threadIdx.x;
    const int b  = blockIdx.y;
    const int q0 = blockIdx.x * 64;
    const float* Qb = Q  + ((size_t)b * SQ + q0) * NF;
    const float* Kb = Km + (size_t)b * SKV * NF;
    const float* Vb = Vm + (size_t)b * SKV * NF;

    // load q tile 64x128
    #pragma unroll
    for (int k = 0; k < 8; k++) {
        int fi = k * 256 + t;
        int r  = fi >> 5;
        int cc = (fi & 31) * 4;
        *(float4*)&qs[r][cc] = *(const float4*)(Qb + (size_t)r * NF + cc);
    }
    if (t < 64) { mrow[t] = -1e30f; lrow[t] = 0.f; }

    const int tqS = t >> 4;   // S-compute: q rows tqS*4+i
    const int tkS = t & 15;   // S-compute: k rows tkS+16*j (stride-16 spread)
    const int tq  = t >> 5;   // O-update: q rows tq*8+i
    const int tf  = t & 31;   // O-update: feats tf*4..tf*4+3

    float4 oacc[8];
    #pragma unroll
    for (int i = 0; i < 8; i++) oacc[i] = make_float4(0.f, 0.f, 0.f, 0.f);

    for (int kv0 = 0; kv0 < SKV; kv0 += 64) {
        __syncthreads();    // previous iteration's readers are done
        #pragma unroll
        for (int k = 0; k < 8; k++) {
            int fi = k * 256 + t;
            int r  = fi >> 5;
            int cc = (fi & 31) * 4;
            *(float4*)&ks[r][cc] = *(const float4*)(Kb + (size_t)(kv0 + r) * NF + cc);
            *(float4*)&vs[r][cc] = *(const float4*)(Vb + (size_t)(kv0 + r) * NF + cc);
        }
        __syncthreads();

        // S = q @ k^T, each thread 4x4
        float s[4][4];
        #pragma unroll
        for (int i = 0; i < 4; i++)
            #pragma unroll
            for (int j = 0; j < 4; j++) s[i][j] = 0.f;
        #pragma unroll 4
        for (int c = 0; c < NF; c += 4) {
            float4 qv[4], kv4[4];
            #pragma unroll
            for (int i = 0; i < 4; i++) qv[i]  = *(float4*)&qs[tqS * 4 + i][c];
            #pragma unroll
            for (int j = 0; j < 4; j++) kv4[j] = *(float4*)&ks[tkS + 16 * j][c];
            #pragma unroll
            for (int i = 0; i < 4; i++)
                #pragma unroll
                for (int j = 0; j < 4; j++)
                    s[i][j] += qv[i].x * kv4[j].x + qv[i].y * kv4[j].y
                             + qv[i].z * kv4[j].z + qv[i].w * kv4[j].w;
        }
        #pragma unroll
        for (int i = 0; i < 4; i++)
            #pragma unroll
            for (int j = 0; j < 4; j++)
                Ss[tqS * 4 + i][tkS + 16 * j] = s[i][j];
        __syncthreads();

        // online softmax: 4 lanes per row (same wave -> shfl ok, no race:
        // all lanes of a wave read mrow/lrow before seg0 writes)
        {
            int r = t >> 2, seg = t & 3;
            float* row = &Ss[r][seg * 16];
            float lm = row[0];
            #pragma unroll
            for (int e = 1; e < 16; e++) lm = fmaxf(lm, row[e]);
            lm = fmaxf(lm, __shfl_xor(lm, 1));
            lm = fmaxf(lm, __shfl_xor(lm, 2));
            float mold = mrow[r];
            float mnew = fmaxf(mold, lm);
            float ls = 0.f;
            #pragma unroll
            for (int e = 0; e < 16; e++) {
                float p = __expf(row[e] - mnew);
                row[e] = p;
                ls += p;
            }
            ls += __shfl_xor(ls, 1);
            ls += __shfl_xor(ls, 2);
            if (seg == 0) {
                arow[r] = __expf(mold - mnew);
                mrow[r] = mnew;
                lrow[r] = lrow[r] * arow[r] + ls;
            }
        }
        __syncthreads();

        // O = O*alpha + P @ V
        #pragma unroll
        for (int i = 0; i < 8; i++) {
            float al = arow[tq * 8 + i];
            oacc[i].x *= al; oacc[i].y *= al; oacc[i].z *= al; oacc[i].w *= al;
        }
        #pragma unroll 2
        for (int kv = 0; kv < 64; kv++) {
            float4 vv = *(float4*)&vs[kv][tf * 4];
            #pragma unroll
            for (int i = 0; i < 8; i++) {
                float p = Ss[tq * 8 + i][kv];
                oacc[i].x += p * vv.x; oacc[i].y += p * vv.y;
                oacc[i].z += p * vv.z; oacc[i].w += p * vv.w;
            }
        }
    }
    __syncthreads();
    #pragma unroll
    for (int i = 0; i < 8; i++) {
        float inv = 1.f / lrow[tq * 8 + i];
        float4 o = oacc[i];
        o.x *= inv; o.y *= inv; o.z *= inv; o.w *= inv;
        *(float4*)(O + ((size_t)b * SQ + q0 + tq * 8 + i) * NF + tf * 4) = o;
    }
}

// ---------------------------------------------------------------------------
// Kernel 4: BN stats (per-feature sum + sumsq over NQ rows)
// grid = NQ/128, block = 256. stats[0..127]=sum, stats[128..255]=sumsq
// ---------------------------------------------------------------------------
__global__ __launch_bounds__(256) void bn_stats(
    const float* __restrict__ tbuf, float* __restrict__ stats)
{
    __shared__ float red[8][128];
    __shared__ float redq[8][128];
    const int t     = threadIdx.x;
    const int tf    = t & 31;
    const int trow  = t >> 5;
    const int rbase = blockIdx.x * 128;

    float4 s  = make_float4(0.f, 0.f, 0.f, 0.f);
    float4 sq = make_float4(0.f, 0.f, 0.f, 0.f);
    #pragma unroll 4
    for (int it = 0; it < 16; it++) {
        int r = rbase + trow * 16 + it;
        float4 v = *(const float4*)(tbuf + (size_t)r * NF + tf * 4);
        s.x += v.x; s.y += v.y; s.z += v.z; s.w += v.w;
        sq.x += v.x * v.x; sq.y += v.y * v.y;
        sq.z += v.z * v.z; sq.w += v.w * v.w;
    }
    *(float4*)&red[trow][tf * 4]  = s;
    *(float4*)&redq[trow][tf * 4] = sq;
    __syncthreads();
    if (t < 128) {
        float acc = 0.f;
        #pragma unroll
        for (int i = 0; i < 8; i++) acc += red[i][t];
        atomicAdd(&stats[t], acc);
    } else {
        int f = t - 128;
        float acc = 0.f;
        #pragma unroll
        for (int i = 0; i < 8; i++) acc += redq[i][f];
        atomicAdd(&stats[128 + f], acc);
    }
}

// ---------------------------------------------------------------------------
// Kernel 5: out = x_dec + (t - mean) * rsqrt(var+eps) * gamma + beta
// grid = NQ*NF/1024, block = 256 (one float4/thread)
// ---------------------------------------------------------------------------
__global__ __launch_bounds__(256) void bn_finalize(
    const float* __restrict__ tbuf, const float* __restrict__ xdec,
    const float* __restrict__ stats, const float* __restrict__ gamma,
    const float* __restrict__ beta, float* __restrict__ out)
{
    const int g = blockIdx.x * 256 + threadIdx.x;
    const int e = g * 4;
    const int f = e & (NF - 1);
    const float invN = 1.0f / (float)NQ;
    float4 tv = *(const float4*)(tbuf + e);
    float4 xv = *(const float4*)(xdec + e);
    float o[4], tt[4] = {tv.x, tv.y, tv.z, tv.w}, xx[4] = {xv.x, xv.y, xv.z, xv.w};
    #pragma unroll
    for (int u = 0; u < 4; u++) {
        float sum  = stats[f + u];
        float sumq = stats[128 + f + u];
        float mean = sum * invN;
        float var  = sumq * invN - mean * mean;
        float sc   = rsqrtf(var + BN_EPS) * gamma[f + u];
        o[u] = xx[u] + (tt[u] - mean) * sc + beta[f + u];
    }
    float4 ov = make_float4(o[0], o[1], o[2], o[3]);
    *(float4*)(out + e) = ov;
}

// ---------------------------------------------------------------------------
extern "C" void kernel_launch(void* const* d_in, const int* in_sizes, int n_in,
                              void* d_out, int out_size, void* d_ws, size_t ws_size,
                              hipStream_t stream) {
    const float* xdec_feat = (const float*)d_in[0];
    const float* xenc_feat = (const float*)d_in[1];
    const int*   nbr       = (const int*)d_in[2];
    const float* Wp1       = (const float*)d_in[3];
    const float* Wq        = (const float*)d_in[4];
    const float* Wk        = (const float*)d_in[5];
    const float* Wv        = (const float*)d_in[6];
    const float* Wt        = (const float*)d_in[7];
    const float* gamma     = (const float*)d_in[8];
    const float* beta      = (const float*)d_in[9];
    float* out = (float*)d_out;

    float* ws    = (float*)d_ws;
    float* xdec  = ws;                    // NQ*NF      = 2M floats
    float* qbuf  = xdec + (size_t)NQ * NF;     // 2M (reused as tbuf after attn)
    float* kbuf  = qbuf + (size_t)NQ * NF;     // 4M
    float* vbuf  = kbuf + (size_t)NKV * NF;    // 4M
    float* xr    = vbuf + (size_t)NKV * NF;    // 2M
    float* stats = xr + (size_t)NQ * NF;       // 256
    float* tbuf  = qbuf;  // q dead after attention; reuse

    hipMemsetAsync(stats, 0, 256 * sizeof(float), stream);

    p1conv_kernel<<<NQ / 64, 256, 0, stream>>>(xdec_feat, nbr, Wp1, xdec);
    gemm_nf128<<<NQ / 64, 256, 0, stream>>>(xdec, Wq, qbuf, NF);
    gemm_nf128<<<NKV / 64, 256, 0, stream>>>(xenc_feat, Wk, kbuf, CIN);
    gemm_nf128<<<NKV / 64, 256, 0, stream>>>(xenc_feat, Wv, vbuf, CIN);
    attn_kernel<<<dim3(SQ / 64, BATCH), 256, 0, stream>>>(qbuf, kbuf, vbuf, xr);
    gemm_nf128<<<NQ / 64, 256, 0, stream>>>(xr, Wt, tbuf, NF);
    bn_stats<<<NQ / 128, 256, 0, stream>>>(tbuf, stats);
    bn_finalize<<<(NQ * NF) / 1024, 256, 0, stream>>>(tbuf, xdec, stats, gamma, beta, out);
}

// Round 2
// 430.686 us; speedup vs baseline: 2.3779x; 2.3779x over previous
//
#include <hip/hip_runtime.h>
#include <math.h>

#define NQ      16384
#define NKV     32768
#define CIN     64
#define NF      128
#define NOFF    27
#define BATCH   8
#define SQ      2048
#define SKV     4096
#define BN_EPS  1e-4f
#define SPLIT   4
#define KV_PER_SPLIT (SKV / SPLIT)           // 1024
#define TILES_PER_SPLIT (KV_PER_SPLIT / 64)  // 16

typedef unsigned short u16;
typedef __attribute__((ext_vector_type(4))) float f32x4;
typedef __attribute__((ext_vector_type(8))) short s16x8;

__device__ __forceinline__ u16 f2b(float x) {
    union { float f; unsigned u; } c; c.f = x;
    unsigned r = (c.u + 0x7FFFu + ((c.u >> 16) & 1u)) >> 16;
    return (u16)r;
}
__device__ __forceinline__ float b2f(u16 x) {
    union { unsigned u; float f; } c; c.u = ((unsigned)x) << 16;
    return c.f;
}

// ---------------------------------------------------------------------------
// Kernel 1: p1 submanifold conv (fp32, unchanged from R1)
// ---------------------------------------------------------------------------
__global__ __launch_bounds__(256) void p1conv_kernel(
    const float* __restrict__ xfeat, const int* __restrict__ nbr,
    const float* __restrict__ Wp1, float* __restrict__ out)
{
    __shared__ float As[64][68];
    __shared__ float Bs[64][132];
    const int t    = threadIdx.x;
    const int base = blockIdx.x * 64;
    const int ty   = t >> 4;
    const int tx   = t & 15;
    const int pl   = t >> 2;
    const int c0   = (t & 3) * 16;

    float4 acc[4][2];
    #pragma unroll
    for (int i = 0; i < 4; i++) {
        acc[i][0] = make_float4(0.f, 0.f, 0.f, 0.f);
        acc[i][1] = make_float4(0.f, 0.f, 0.f, 0.f);
    }

    for (int ko = 0; ko < NOFF; ko++) {
        __syncthreads();
        int idx = nbr[(size_t)(base + pl) * NOFF + ko];
        const float* srcA = xfeat + (size_t)idx * CIN + c0;
        float4 a0 = *(const float4*)(srcA + 0);
        float4 a1 = *(const float4*)(srcA + 4);
        float4 a2 = *(const float4*)(srcA + 8);
        float4 a3 = *(const float4*)(srcA + 12);
        const float* srcB = Wp1 + (size_t)ko * CIN * NF;
        float4 bv[8];
        #pragma unroll
        for (int k = 0; k < 8; k++) {
            int fi = k * 256 + t;
            bv[k] = *(const float4*)(srcB + fi * 4);
        }
        *(float4*)&As[pl][c0 + 0]  = a0;
        *(float4*)&As[pl][c0 + 4]  = a1;
        *(float4*)&As[pl][c0 + 8]  = a2;
        *(float4*)&As[pl][c0 + 12] = a3;
        #pragma unroll
        for (int k = 0; k < 8; k++) {
            int fi = k * 256 + t;
            int r  = fi >> 5;
            int cc = (fi & 31) * 4;
            *(float4*)&Bs[r][cc] = bv[k];
        }
        __syncthreads();
        #pragma unroll 4
        for (int c = 0; c < 64; c++) {
            float a[4];
            #pragma unroll
            for (int i = 0; i < 4; i++) a[i] = As[ty * 4 + i][c];
            float4 b0 = *(float4*)&Bs[c][tx * 4];
            float4 b1 = *(float4*)&Bs[c][tx * 4 + 64];
            #pragma unroll
            for (int i = 0; i < 4; i++) {
                acc[i][0].x += a[i] * b0.x; acc[i][0].y += a[i] * b0.y;
                acc[i][0].z += a[i] * b0.z; acc[i][0].w += a[i] * b0.w;
                acc[i][1].x += a[i] * b1.x; acc[i][1].y += a[i] * b1.y;
                acc[i][1].z += a[i] * b1.z; acc[i][1].w += a[i] * b1.w;
            }
        }
    }
    #pragma unroll
    for (int i = 0; i < 4; i++) {
        float* dst = out + (size_t)(base + ty * 4 + i) * NF;
        *(float4*)(dst + tx * 4)      = acc[i][0];
        *(float4*)(dst + tx * 4 + 64) = acc[i][1];
    }
}

// ---------------------------------------------------------------------------
// Kernel 2: C[M,128] = A[M,K] @ W[K,128].  MODE 0: fp32 row-major out.
// MODE 1: bf16 row-major out.  MODE 2: bf16 transposed per-batch (V^T) out.
// ---------------------------------------------------------------------------
template<int MODE>
__global__ __launch_bounds__(256) void gemm_nf128(
    const float* __restrict__ A, const float* __restrict__ W,
    void* __restrict__ Cout, int K)
{
    __shared__ float As[64][68];
    __shared__ float Bs[64][132];
    const int t    = threadIdx.x;
    const int base = blockIdx.x * 64;
    const int ty   = t >> 4;
    const int tx   = t & 15;
    const int pl   = t >> 2;
    const int c0   = (t & 3) * 16;

    float4 acc[4][2];
    #pragma unroll
    for (int i = 0; i < 4; i++) {
        acc[i][0] = make_float4(0.f, 0.f, 0.f, 0.f);
        acc[i][1] = make_float4(0.f, 0.f, 0.f, 0.f);
    }

    for (int k0 = 0; k0 < K; k0 += 64) {
        __syncthreads();
        const float* srcA = A + (size_t)(base + pl) * K + k0 + c0;
        float4 a0 = *(const float4*)(srcA + 0);
        float4 a1 = *(const float4*)(srcA + 4);
        float4 a2 = *(const float4*)(srcA + 8);
        float4 a3 = *(const float4*)(srcA + 12);
        float4 bv[8];
        #pragma unroll
        for (int k = 0; k < 8; k++) {
            int fi = k * 256 + t;
            int r  = fi >> 5;
            int cc = (fi & 31) * 4;
            bv[k] = *(const float4*)(W + (size_t)(k0 + r) * NF + cc);
        }
        *(float4*)&As[pl][c0 + 0]  = a0;
        *(float4*)&As[pl][c0 + 4]  = a1;
        *(float4*)&As[pl][c0 + 8]  = a2;
        *(float4*)&As[pl][c0 + 12] = a3;
        #pragma unroll
        for (int k = 0; k < 8; k++) {
            int fi = k * 256 + t;
            int r  = fi >> 5;
            int cc = (fi & 31) * 4;
            *(float4*)&Bs[r][cc] = bv[k];
        }
        __syncthreads();
        #pragma unroll 4
        for (int c = 0; c < 64; c++) {
            float a[4];
            #pragma unroll
            for (int i = 0; i < 4; i++) a[i] = As[ty * 4 + i][c];
            float4 b0 = *(float4*)&Bs[c][tx * 4];
            float4 b1 = *(float4*)&Bs[c][tx * 4 + 64];
            #pragma unroll
            for (int i = 0; i < 4; i++) {
                acc[i][0].x += a[i] * b0.x; acc[i][0].y += a[i] * b0.y;
                acc[i][0].z += a[i] * b0.z; acc[i][0].w += a[i] * b0.w;
                acc[i][1].x += a[i] * b1.x; acc[i][1].y += a[i] * b1.y;
                acc[i][1].z += a[i] * b1.z; acc[i][1].w += a[i] * b1.w;
            }
        }
    }
    if (MODE == 0) {
        float* C = (float*)Cout;
        #pragma unroll
        for (int i = 0; i < 4; i++) {
            float* dst = C + (size_t)(base + ty * 4 + i) * NF;
            *(float4*)(dst + tx * 4)      = acc[i][0];
            *(float4*)(dst + tx * 4 + 64) = acc[i][1];
        }
    } else if (MODE == 1) {
        u16* C = (u16*)Cout;
        #pragma unroll
        for (int i = 0; i < 4; i++) {
            u16* dst = C + (size_t)(base + ty * 4 + i) * NF;
            #pragma unroll
            for (int h = 0; h < 2; h++) {
                const float* a = (const float*)&acc[i][h];
                ushort4 pk;
                pk.x = f2b(a[0]); pk.y = f2b(a[1]); pk.z = f2b(a[2]); pk.w = f2b(a[3]);
                *(ushort4*)(dst + tx * 4 + 64 * h) = pk;
            }
        }
    } else {
        // V^T: vt[b][f][kv], f in [0,128), kv in [0,4096)
        u16* C = (u16*)Cout;
        int r0 = base + ty * 4;
        int bb = r0 >> 12;
        int kv = r0 & 4095;
        #pragma unroll
        for (int h = 0; h < 2; h++) {
            #pragma unroll
            for (int u = 0; u < 4; u++) {
                ushort4 pk;
                pk.x = f2b(((const float*)&acc[0][h])[u]);
                pk.y = f2b(((const float*)&acc[1][h])[u]);
                pk.z = f2b(((const float*)&acc[2][h])[u]);
                pk.w = f2b(((const float*)&acc[3][h])[u]);
                *(ushort4*)(C + ((size_t)(bb * NF + tx * 4 + u + 64 * h)) * SKV + kv) = pk;
            }
        }
    }
}

// ---------------------------------------------------------------------------
// Kernel 3: MFMA flash attention, bf16 in, bf16 unnormalized partials out.
// grid = (SQ/64, BATCH, SPLIT), block = 256 (4 waves, 16 q-rows each).
// K tile + V^T tile staged in LDS (shared by the 4 waves); P round-trips
// through wave-private LDS to convert C-layout -> A-layout (m120 pattern).
// ---------------------------------------------------------------------------
__global__ __launch_bounds__(256, 3) void attn_mfma_kernel(
    const u16* __restrict__ Q, const u16* __restrict__ K,
    const u16* __restrict__ Vt, u16* __restrict__ Opart,
    float* __restrict__ mpart, float* __restrict__ lpart)
{
    __shared__ u16 Ks[64][136];     // row stride 272B = 17*16 (aligned, 4-dw skew)
    __shared__ u16 Vs[128][72];     // row stride 144B = 9*16
    __shared__ u16 Ps[4][16][72];   // per-wave P buffer

    const int t    = threadIdx.x;
    const int b    = blockIdx.y;
    const int q0   = blockIdx.x * 64;
    const int sp   = blockIdx.z;
    const int w    = t >> 6;
    const int lane = t & 63;
    const int quad = lane >> 4;
    const int l15  = lane & 15;

    const u16* Kb  = K  + (size_t)b * SKV * NF;
    const u16* Vtb = Vt + (size_t)b * NF * SKV;

    const int kvr = t >> 2, seg = t & 3;   // K staging: row kvr, 64B segment
    const int vf  = t >> 1, vh  = t & 1;   // V staging: row vf, 64B half

    // Q fragments (A-operand: m=lane&15, k=quad*8+j)
    const u16* Qp = Q + ((size_t)(b * SQ + q0 + w * 16 + l15)) * NF + quad * 8;
    s16x8 qf[4];
    #pragma unroll
    for (int ks = 0; ks < 4; ks++) qf[ks] = *(const s16x8*)(Qp + ks * 32);

    f32x4 oacc[8];
    #pragma unroll
    for (int n = 0; n < 8; n++) oacc[n] = (f32x4)0.f;
    float mrow[4] = {-1e30f, -1e30f, -1e30f, -1e30f};
    float lrow[4] = {0.f, 0.f, 0.f, 0.f};

    const int kvbase = sp * KV_PER_SPLIT;
    uint4 kreg[4], vreg[4];
    {
        const u16* kp = Kb + (size_t)(kvbase + kvr) * NF + seg * 32;
        const u16* vp = Vtb + (size_t)vf * SKV + kvbase + vh * 32;
        #pragma unroll
        for (int i = 0; i < 4; i++) {
            kreg[i] = *(const uint4*)(kp + i * 8);
            vreg[i] = *(const uint4*)(vp + i * 8);
        }
    }

    for (int tile = 0; tile < TILES_PER_SPLIT; tile++) {
        __syncthreads();
        #pragma unroll
        for (int i = 0; i < 4; i++) {
            *(uint4*)&Ks[kvr][seg * 32 + i * 8] = kreg[i];
            *(uint4*)&Vs[vf][vh * 32 + i * 8]   = vreg[i];
        }
        __syncthreads();
        if (tile + 1 < TILES_PER_SPLIT) {
            int kvn = kvbase + (tile + 1) * 64;
            const u16* kp = Kb + (size_t)(kvn + kvr) * NF + seg * 32;
            const u16* vp = Vtb + (size_t)vf * SKV + kvn + vh * 32;
            #pragma unroll
            for (int i = 0; i < 4; i++) {
                kreg[i] = *(const uint4*)(kp + i * 8);
                vreg[i] = *(const uint4*)(vp + i * 8);
            }
        }

        // S = Q K^T : D[row=quad*4+r = q][col=l15 = kv]
        f32x4 sacc[4];
        #pragma unroll
        for (int c = 0; c < 4; c++) {
            sacc[c] = (f32x4)0.f;
            #pragma unroll
            for (int ks = 0; ks < 4; ks++) {
                s16x8 kb = *(const s16x8*)&Ks[c * 16 + l15][ks * 32 + quad * 8];
                sacc[c] = __builtin_amdgcn_mfma_f32_16x16x32_bf16(qf[ks], kb, sacc[c], 0, 0, 0);
            }
        }

        // online softmax over the 64 kv of this tile
        float pv[4][4];
        float alpha[4];
        #pragma unroll
        for (int r = 0; r < 4; r++) {
            float mx = fmaxf(fmaxf(sacc[0][r], sacc[1][r]), fmaxf(sacc[2][r], sacc[3][r]));
            mx = fmaxf(mx, __shfl_xor(mx, 1));
            mx = fmaxf(mx, __shfl_xor(mx, 2));
            mx = fmaxf(mx, __shfl_xor(mx, 4));
            mx = fmaxf(mx, __shfl_xor(mx, 8));
            float mnew = fmaxf(mrow[r], mx);
            alpha[r] = __expf(mrow[r] - mnew);
            float rs = 0.f;
            #pragma unroll
            for (int c = 0; c < 4; c++) {
                float p = __expf(sacc[c][r] - mnew);
                pv[c][r] = p;
                rs += p;
            }
            rs += __shfl_xor(rs, 1);
            rs += __shfl_xor(rs, 2);
            rs += __shfl_xor(rs, 4);
            rs += __shfl_xor(rs, 8);
            lrow[r] = lrow[r] * alpha[r] + rs;
            mrow[r] = mnew;
        }

        // P: C-layout regs -> wave-private LDS (bf16)
        #pragma unroll
        for (int c = 0; c < 4; c++)
            #pragma unroll
            for (int r = 0; r < 4; r++)
                Ps[w][quad * 4 + r][c * 16 + l15] = f2b(pv[c][r]);

        // rescale O
        #pragma unroll
        for (int n = 0; n < 8; n++)
            #pragma unroll
            for (int r = 0; r < 4; r++)
                oacc[n][r] *= alpha[r];

        // O += P @ V  (A = P from LDS in A-layout, B = V^T rows)
        s16x8 pa0 = *(const s16x8*)&Ps[w][l15][quad * 8];
        s16x8 pa1 = *(const s16x8*)&Ps[w][l15][32 + quad * 8];
        #pragma unroll
        for (int n = 0; n < 8; n++) {
            s16x8 vb0 = *(const s16x8*)&Vs[n * 16 + l15][quad * 8];
            s16x8 vb1 = *(const s16x8*)&Vs[n * 16 + l15][32 + quad * 8];
            oacc[n] = __builtin_amdgcn_mfma_f32_16x16x32_bf16(pa0, vb0, oacc[n], 0, 0, 0);
            oacc[n] = __builtin_amdgcn_mfma_f32_16x16x32_bf16(pa1, vb1, oacc[n], 0, 0, 0);
        }
    }

    // epilogue: unnormalized O partial (bf16) + m,l per row
    u16* Ob = Opart + (size_t)sp * NQ * NF;
    #pragma unroll
    for (int r = 0; r < 4; r++) {
        int grow = b * SQ + q0 + w * 16 + quad * 4 + r;
        #pragma unroll
        for (int n = 0; n < 8; n++)
            Ob[(size_t)grow * NF + n * 16 + l15] = f2b(oacc[n][r]);
        if (l15 == 0) {
            mpart[sp * NQ + grow] = mrow[r];
            lpart[sp * NQ + grow] = lrow[r];
        }
    }
}

// ---------------------------------------------------------------------------
// Kernel 3b: merge the SPLIT partials -> x_r fp32
// grid = NQ*32/256, block 256; each thread does 4 cols of one row.
// ---------------------------------------------------------------------------
__global__ __launch_bounds__(256) void attn_merge_kernel(
    const u16* __restrict__ Opart, const float* __restrict__ mpart,
    const float* __restrict__ lpart, float* __restrict__ xr)
{
    int idx = blockIdx.x * 256 + threadIdx.x;
    int row = idx >> 5;
    int c4  = (idx & 31) * 4;
    float m[SPLIT], l[SPLIT];
    #pragma unroll
    for (int s = 0; s < SPLIT; s++) {
        m[s] = mpart[s * NQ + row];
        l[s] = lpart[s * NQ + row];
    }
    float M = m[0];
    #pragma unroll
    for (int s = 1; s < SPLIT; s++) M = fmaxf(M, m[s]);
    float L = 0.f, wgt[SPLIT];
    #pragma unroll
    for (int s = 0; s < SPLIT; s++) {
        wgt[s] = __expf(m[s] - M);
        L += l[s] * wgt[s];
    }
    float o0 = 0.f, o1 = 0.f, o2 = 0.f, o3 = 0.f;
    #pragma unroll
    for (int s = 0; s < SPLIT; s++) {
        ushort4 u = *(const ushort4*)(Opart + (size_t)s * NQ * NF + (size_t)row * NF + c4);
        o0 += wgt[s] * b2f(u.x); o1 += wgt[s] * b2f(u.y);
        o2 += wgt[s] * b2f(u.z); o3 += wgt[s] * b2f(u.w);
    }
    float inv = 1.f / L;
    float4 o = make_float4(o0 * inv, o1 * inv, o2 * inv, o3 * inv);
    *(float4*)(xr + (size_t)row * NF + c4) = o;
}

// ---------------------------------------------------------------------------
// Kernel 4: BN stats (unchanged)
// ---------------------------------------------------------------------------
__global__ __launch_bounds__(256) void bn_stats(
    const float* __restrict__ tbuf, float* __restrict__ stats)
{
    __shared__ float red[8][128];
    __shared__ float redq[8][128];
    const int t     = threadIdx.x;
    const int tf    = t & 31;
    const int trow  = t >> 5;
    const int rbase = blockIdx.x * 128;

    float4 s  = make_float4(0.f, 0.f, 0.f, 0.f);
    float4 sq = make_float4(0.f, 0.f, 0.f, 0.f);
    #pragma unroll 4
    for (int it = 0; it < 16; it++) {
        int r = rbase + trow * 16 + it;
        float4 v = *(const float4*)(tbuf + (size_t)r * NF + tf * 4);
        s.x += v.x; s.y += v.y; s.z += v.z; s.w += v.w;
        sq.x += v.x * v.x; sq.y += v.y * v.y;
        sq.z += v.z * v.z; sq.w += v.w * v.w;
    }
    *(float4*)&red[trow][tf * 4]  = s;
    *(float4*)&redq[trow][tf * 4] = sq;
    __syncthreads();
    if (t < 128) {
        float acc = 0.f;
        #pragma unroll
        for (int i = 0; i < 8; i++) acc += red[i][t];
        atomicAdd(&stats[t], acc);
    } else {
        int f = t - 128;
        float acc = 0.f;
        #pragma unroll
        for (int i = 0; i < 8; i++) acc += redq[i][f];
        atomicAdd(&stats[128 + f], acc);
    }
}

// ---------------------------------------------------------------------------
// Kernel 5: out = x_dec + BN(t) (unchanged)
// ---------------------------------------------------------------------------
__global__ __launch_bounds__(256) void bn_finalize(
    const float* __restrict__ tbuf, const float* __restrict__ xdec,
    const float* __restrict__ stats, const float* __restrict__ gamma,
    const float* __restrict__ beta, float* __restrict__ out)
{
    const int g = blockIdx.x * 256 + threadIdx.x;
    const int e = g * 4;
    const int f = e & (NF - 1);
    const float invN = 1.0f / (float)NQ;
    float4 tv = *(const float4*)(tbuf + e);
    float4 xv = *(const float4*)(xdec + e);
    float o[4], tt[4] = {tv.x, tv.y, tv.z, tv.w}, xx[4] = {xv.x, xv.y, xv.z, xv.w};
    #pragma unroll
    for (int u = 0; u < 4; u++) {
        float sum  = stats[f + u];
        float sumq = stats[128 + f + u];
        float mean = sum * invN;
        float var  = sumq * invN - mean * mean;
        float sc   = rsqrtf(var + BN_EPS) * gamma[f + u];
        o[u] = xx[u] + (tt[u] - mean) * sc + beta[f + u];
    }
    float4 ov = make_float4(o[0], o[1], o[2], o[3]);
    *(float4*)(out + e) = ov;
}

// ---------------------------------------------------------------------------
extern "C" void kernel_launch(void* const* d_in, const int* in_sizes, int n_in,
                              void* d_out, int out_size, void* d_ws, size_t ws_size,
                              hipStream_t stream) {
    const float* xdec_feat = (const float*)d_in[0];
    const float* xenc_feat = (const float*)d_in[1];
    const int*   nbr       = (const int*)d_in[2];
    const float* Wp1       = (const float*)d_in[3];
    const float* Wq        = (const float*)d_in[4];
    const float* Wk        = (const float*)d_in[5];
    const float* Wv        = (const float*)d_in[6];
    const float* Wt        = (const float*)d_in[7];
    const float* gamma     = (const float*)d_in[8];
    const float* beta      = (const float*)d_in[9];
    float* out = (float*)d_out;

    // workspace layout (bytes)
    char* wsb = (char*)d_ws;
    const size_t MB = 1024 * 1024;
    float* xdec  = (float*)(wsb + 0);            //  0..8M   fp32 NQ*NF
    u16*   qbuf  = (u16*)  (wsb + 8 * MB);       //  8..12M  bf16 NQ*NF
    u16*   kbuf  = (u16*)  (wsb + 12 * MB);      // 12..20M  bf16 NKV*NF
    u16*   vt    = (u16*)  (wsb + 20 * MB);      // 20..28M  bf16 NKV*NF (transposed per batch)
    u16*   opart = (u16*)  (wsb + 28 * MB);      // 28..44M  bf16 SPLIT*NQ*NF
    float* mpart = (float*)(wsb + 44 * MB);      // 256K
    float* lpart = (float*)(wsb + 44 * MB + 256 * 1024);
    float* stats = (float*)(wsb + 44 * MB + 512 * 1024);
    float* xr    = (float*)(wsb + 20 * MB);      // reuses vt (dead after attn)
    float* tbuf  = (float*)(wsb + 8 * MB);       // reuses qbuf+kbuf (dead after attn)

    hipMemsetAsync(stats, 0, 256 * sizeof(float), stream);

    p1conv_kernel<<<NQ / 64, 256, 0, stream>>>(xdec_feat, nbr, Wp1, xdec);
    gemm_nf128<1><<<NQ / 64, 256, 0, stream>>>(xdec, Wq, (void*)qbuf, NF);
    gemm_nf128<1><<<NKV / 64, 256, 0, stream>>>(xenc_feat, Wk, (void*)kbuf, CIN);
    gemm_nf128<2><<<NKV / 64, 256, 0, stream>>>(xenc_feat, Wv, (void*)vt, CIN);
    attn_mfma_kernel<<<dim3(SQ / 64, BATCH, SPLIT), 256, 0, stream>>>(
        qbuf, kbuf, vt, opart, mpart, lpart);
    attn_merge_kernel<<<(NQ * 32) / 256, 256, 0, stream>>>(opart, mpart, lpart, xr);
    gemm_nf128<0><<<NQ / 64, 256, 0, stream>>>(xr, Wt, (void*)tbuf, NF);
    bn_stats<<<NQ / 128, 256, 0, stream>>>(tbuf, stats);
    bn_finalize<<<(NQ * NF) / 1024, 256, 0, stream>>>(tbuf, xdec, stats, gamma, beta, out);
}

// Round 3
// 227.611 us; speedup vs baseline: 4.4994x; 1.8922x over previous
//
#include <hip/hip_runtime.h>
#include <math.h>

#define NQ      16384
#define NKV     32768
#define CIN     64
#define NF      128
#define NOFF    27
#define BATCH   8
#define SQ      2048
#define SKV     4096
#define BN_EPS  1e-4f
#define SPLIT   4
#define KV_PER_SPLIT (SKV / SPLIT)           // 1024
#define TILES_PER_SPLIT (KV_PER_SPLIT / 64)  // 16

typedef unsigned short u16;
typedef __attribute__((ext_vector_type(4))) float f32x4;
typedef __attribute__((ext_vector_type(8))) short s16x8;

__device__ __forceinline__ u16 f2b(float x) {
    union { float f; unsigned u; } c; c.f = x;
    unsigned r = (c.u + 0x7FFFu + ((c.u >> 16) & 1u)) >> 16;
    return (u16)r;
}
__device__ __forceinline__ float b2f(u16 x) {
    union { unsigned u; float f; } c; c.u = ((unsigned)x) << 16;
    return c.f;
}
// async global->LDS, 16B per lane; dest = wave-uniform base + lane*16
__device__ __forceinline__ void g2l16(const void* gp, void* lp) {
    __builtin_amdgcn_global_load_lds(
        (const __attribute__((address_space(1))) unsigned*)gp,
        (__attribute__((address_space(3))) unsigned*)lp, 16, 0, 0);
}

// ---------------------------------------------------------------------------
// cvt: fp32 -> bf16 flat (n multiple of 1024)
// ---------------------------------------------------------------------------
__global__ __launch_bounds__(256) void cvt_bf16_kernel(
    const float* __restrict__ src, u16* __restrict__ dst)
{
    int i = (blockIdx.x * 256 + threadIdx.x) * 4;
    float4 v = *(const float4*)(src + i);
    ushort4 o;
    o.x = f2b(v.x); o.y = f2b(v.y); o.z = f2b(v.z); o.w = f2b(v.w);
    *(ushort4*)(dst + i) = o;
}

// ---------------------------------------------------------------------------
// cvt Wp1[27][64][128] fp32 -> wp1t[27][128][64] bf16 (transposed)
// one thread per 4 output c's. grid = 27*128*16/256 = 216
// ---------------------------------------------------------------------------
__global__ __launch_bounds__(256) void cvt_wp1t_kernel(
    const float* __restrict__ src, u16* __restrict__ dst)
{
    int id = blockIdx.x * 256 + threadIdx.x;      // 27*128*16 = 55296
    int ko = id >> 11;
    int r  = id & 2047;
    int f  = r >> 4;
    int c4 = (r & 15) * 4;
    const float* s = src + (size_t)ko * 8192 + (size_t)c4 * NF + f;
    ushort4 o;
    o.x = f2b(s[0]); o.y = f2b(s[NF]); o.z = f2b(s[2 * NF]); o.w = f2b(s[3 * NF]);
    *(ushort4*)(dst + (size_t)ko * 8192 + (size_t)f * 64 + c4) = o;
}

// ---------------------------------------------------------------------------
// Kernel 1: p1 conv via MFMA. grid = (NQ/64, 2), block 256 (4 waves x 16 pts).
// Each block: 64 points x 64 feats (fh = blockIdx.y selects feature half).
// A = gathered xf (bf16), B = wp1t[ko] rows [f][c]. XOR-swizzled LDS,
// staged with global_load_lds.
// ---------------------------------------------------------------------------
__global__ __launch_bounds__(256, 3) void p1conv_mfma_kernel(
    const u16* __restrict__ xf, const int* __restrict__ nbr,
    const u16* __restrict__ wt, float* __restrict__ out)
{
    __shared__ u16 As[64][64];      // [pt][c] phys chunk = k8 ^ (row&7)
    __shared__ u16 Bs[64][64];      // [f][c]  phys chunk = k8 ^ (row&7)
    __shared__ int nbr_s[64][28];

    const int t    = threadIdx.x;
    const int w    = t >> 6;
    const int lane = t & 63;
    const int quad = lane >> 4;
    const int l15  = lane & 15;
    const int base = blockIdx.x * 64;
    const int fh   = blockIdx.y;

    for (int i = t; i < 64 * NOFF; i += 256)
        nbr_s[i / NOFF][i % NOFF] = nbr[(size_t)base * NOFF + i];

    f32x4 oacc[4];
    #pragma unroll
    for (int n = 0; n < 4; n++) oacc[n] = (f32x4)0.f;

    __syncthreads();   // nbr_s ready

    for (int ko = 0; ko < NOFF; ko++) {
        if (ko) __syncthreads();    // previous tile's readers done
        #pragma unroll
        for (int c = 0; c < 2; c++) {
            int row = w * 16 + c * 8 + (lane >> 3);
            int k8  = (lane & 7) ^ (row & 7);
            int nb  = nbr_s[row][ko];
            g2l16(xf + (size_t)nb * CIN + k8 * 8, &As[w * 16 + c * 8][0]);
        }
        #pragma unroll
        for (int c = 0; c < 2; c++) {
            int row = w * 16 + c * 8 + (lane >> 3);
            int k8  = (lane & 7) ^ (row & 7);
            g2l16(wt + (size_t)ko * 8192 + (size_t)(fh * 64 + row) * 64 + k8 * 8,
                  &Bs[w * 16 + c * 8][0]);
        }
        __syncthreads();

        s16x8 af[2];
        #pragma unroll
        for (int ks = 0; ks < 2; ks++) {
            int p = (ks * 4 + quad) ^ (l15 & 7);
            af[ks] = *(const s16x8*)&As[w * 16 + l15][p * 8];
        }
        #pragma unroll
        for (int nt = 0; nt < 4; nt++) {
            #pragma unroll
            for (int ks = 0; ks < 2; ks++) {
                int p = (ks * 4 + quad) ^ (l15 & 7);
                s16x8 bf = *(const s16x8*)&Bs[nt * 16 + l15][p * 8];
                oacc[nt] = __builtin_amdgcn_mfma_f32_16x16x32_bf16(af[ks], bf, oacc[nt], 0, 0, 0);
            }
        }
    }
    // D[m=pt: quad*4+r][n=f: nt*16+l15]
    #pragma unroll
    for (int nt = 0; nt < 4; nt++)
        #pragma unroll
        for (int r = 0; r < 4; r++)
            out[(size_t)(base + w * 16 + quad * 4 + r) * NF + fh * 64 + nt * 16 + l15] = oacc[nt][r];
}

// ---------------------------------------------------------------------------
// Kernel 2: C[M,128] = A[M,K] @ W[K,128]. MODE 0 fp32, 1 bf16, 2 bf16 V^T.
// ---------------------------------------------------------------------------
template<int MODE>
__global__ __launch_bounds__(256) void gemm_nf128(
    const float* __restrict__ A, const float* __restrict__ W,
    void* __restrict__ Cout, int K)
{
    __shared__ float As[64][68];
    __shared__ float Bs[64][132];
    const int t    = threadIdx.x;
    const int base = blockIdx.x * 64;
    const int ty   = t >> 4;
    const int tx   = t & 15;
    const int pl   = t >> 2;
    const int c0   = (t & 3) * 16;

    float4 acc[4][2];
    #pragma unroll
    for (int i = 0; i < 4; i++) {
        acc[i][0] = make_float4(0.f, 0.f, 0.f, 0.f);
        acc[i][1] = make_float4(0.f, 0.f, 0.f, 0.f);
    }

    for (int k0 = 0; k0 < K; k0 += 64) {
        __syncthreads();
        const float* srcA = A + (size_t)(base + pl) * K + k0 + c0;
        float4 a0 = *(const float4*)(srcA + 0);
        float4 a1 = *(const float4*)(srcA + 4);
        float4 a2 = *(const float4*)(srcA + 8);
        float4 a3 = *(const float4*)(srcA + 12);
        float4 bv[8];
        #pragma unroll
        for (int k = 0; k < 8; k++) {
            int fi = k * 256 + t;
            int r  = fi >> 5;
            int cc = (fi & 31) * 4;
            bv[k] = *(const float4*)(W + (size_t)(k0 + r) * NF + cc);
        }
        *(float4*)&As[pl][c0 + 0]  = a0;
        *(float4*)&As[pl][c0 + 4]  = a1;
        *(float4*)&As[pl][c0 + 8]  = a2;
        *(float4*)&As[pl][c0 + 12] = a3;
        #pragma unroll
        for (int k = 0; k < 8; k++) {
            int fi = k * 256 + t;
            int r  = fi >> 5;
            int cc = (fi & 31) * 4;
            *(float4*)&Bs[r][cc] = bv[k];
        }
        __syncthreads();
        #pragma unroll 4
        for (int c = 0; c < 64; c++) {
            float a[4];
            #pragma unroll
            for (int i = 0; i < 4; i++) a[i] = As[ty * 4 + i][c];
            float4 b0 = *(float4*)&Bs[c][tx * 4];
            float4 b1 = *(float4*)&Bs[c][tx * 4 + 64];
            #pragma unroll
            for (int i = 0; i < 4; i++) {
                acc[i][0].x += a[i] * b0.x; acc[i][0].y += a[i] * b0.y;
                acc[i][0].z += a[i] * b0.z; acc[i][0].w += a[i] * b0.w;
                acc[i][1].x += a[i] * b1.x; acc[i][1].y += a[i] * b1.y;
                acc[i][1].z += a[i] * b1.z; acc[i][1].w += a[i] * b1.w;
            }
        }
    }
    if (MODE == 0) {
        float* C = (float*)Cout;
        #pragma unroll
        for (int i = 0; i < 4; i++) {
            float* dst = C + (size_t)(base + ty * 4 + i) * NF;
            *(float4*)(dst + tx * 4)      = acc[i][0];
            *(float4*)(dst + tx * 4 + 64) = acc[i][1];
        }
    } else if (MODE == 1) {
        u16* C = (u16*)Cout;
        #pragma unroll
        for (int i = 0; i < 4; i++) {
            u16* dst = C + (size_t)(base + ty * 4 + i) * NF;
            #pragma unroll
            for (int h = 0; h < 2; h++) {
                const float* a = (const float*)&acc[i][h];
                ushort4 pk;
                pk.x = f2b(a[0]); pk.y = f2b(a[1]); pk.z = f2b(a[2]); pk.w = f2b(a[3]);
                *(ushort4*)(dst + tx * 4 + 64 * h) = pk;
            }
        }
    } else {
        u16* C = (u16*)Cout;
        int r0 = base + ty * 4;
        int bb = r0 >> 12;
        int kv = r0 & 4095;
        #pragma unroll
        for (int h = 0; h < 2; h++) {
            #pragma unroll
            for (int u = 0; u < 4; u++) {
                ushort4 pk;
                pk.x = f2b(((const float*)&acc[0][h])[u]);
                pk.y = f2b(((const float*)&acc[1][h])[u]);
                pk.z = f2b(((const float*)&acc[2][h])[u]);
                pk.w = f2b(((const float*)&acc[3][h])[u]);
                *(ushort4*)(C + ((size_t)(bb * NF + tx * 4 + u + 64 * h)) * SKV + kv) = pk;
            }
        }
    }
}

// ---------------------------------------------------------------------------
// Kernel 3: MFMA flash attention (swapped-operand form).
// Computes S^T = K Q^T and O^T = V^T P^T. Per-lane softmax state (q = l15).
// grid = (SQ/64, BATCH, SPLIT), block 256.
// ---------------------------------------------------------------------------
__global__ __launch_bounds__(256, 3) void attn_mfma_kernel(
    const u16* __restrict__ Q, const u16* __restrict__ K,
    const u16* __restrict__ Vt, u16* __restrict__ Opart,
    float* __restrict__ mpart, float* __restrict__ lpart)
{
    __shared__ u16 Ks[64][128];     // [kv][f]  phys chunk = k8 ^ (row&15)
    __shared__ u16 Vs[128][64];     // [f][kv]  phys chunk = k8 ^ (row&7)
    __shared__ u16 Ps[4][16][72];   // [wave][q][kv], padded stride 72

    const int t    = threadIdx.x;
    const int b    = blockIdx.y;
    const int q0   = blockIdx.x * 64;
    const int sp   = blockIdx.z;
    const int w    = t >> 6;
    const int lane = t & 63;
    const int quad = lane >> 4;
    const int l15  = lane & 15;

    const u16* Kb  = K  + (size_t)b * SKV * NF;
    const u16* Vtb = Vt + (size_t)b * NF * SKV;

    // Q as B-operand: lane l15 = q row, regs = k
    const u16* Qp = Q + ((size_t)(b * SQ + q0 + w * 16 + l15)) * NF + quad * 8;
    s16x8 qf[4];
    #pragma unroll
    for (int ks = 0; ks < 4; ks++) qf[ks] = *(const s16x8*)(Qp + ks * 32);

    f32x4 oacc[8];
    #pragma unroll
    for (int n = 0; n < 8; n++) oacc[n] = (f32x4)0.f;
    float mrow = -1e30f, lrow = 0.f;    // q = w*16 + l15 (per lane)

    const int kvbase = sp * KV_PER_SPLIT;

    for (int tile = 0; tile < TILES_PER_SPLIT; tile++) {
        int kv0 = kvbase + tile * 64;
        __syncthreads();
        #pragma unroll
        for (int c = 0; c < 4; c++) {
            int row = w * 16 + c * 4 + (lane >> 4);
            int k8  = (lane & 15) ^ (row & 15);
            g2l16(Kb + (size_t)(kv0 + row) * NF + k8 * 8, &Ks[w * 16 + c * 4][0]);
        }
        #pragma unroll
        for (int c = 0; c < 4; c++) {
            int row = w * 32 + c * 8 + (lane >> 3);
            int k8  = (lane & 7) ^ (row & 7);
            g2l16(Vtb + (size_t)row * SKV + kv0 + k8 * 8, &Vs[w * 32 + c * 8][0]);
        }
        __syncthreads();

        // S^T[kv = c*16+quad*4+r][q = l15]
        f32x4 sacc[4];
        #pragma unroll
        for (int c = 0; c < 4; c++) {
            sacc[c] = (f32x4)0.f;
            #pragma unroll
            for (int ks = 0; ks < 4; ks++) {
                int p = (ks * 4 + quad) ^ l15;
                s16x8 ka = *(const s16x8*)&Ks[c * 16 + l15][p * 8];
                sacc[c] = __builtin_amdgcn_mfma_f32_16x16x32_bf16(ka, qf[ks], sacc[c], 0, 0, 0);
            }
        }

        // online softmax: 16 kv in-lane + quad-group shuffles
        float mx = sacc[0][0];
        #pragma unroll
        for (int c = 0; c < 4; c++)
            #pragma unroll
            for (int r = 0; r < 4; r++) mx = fmaxf(mx, sacc[c][r]);
        mx = fmaxf(mx, __shfl_xor(mx, 16));
        mx = fmaxf(mx, __shfl_xor(mx, 32));
        float mnew  = fmaxf(mrow, mx);
        float alpha = __expf(mrow - mnew);
        float pv[4][4];
        float rs = 0.f;
        #pragma unroll
        for (int c = 0; c < 4; c++)
            #pragma unroll
            for (int r = 0; r < 4; r++) {
                float p = __expf(sacc[c][r] - mnew);
                pv[c][r] = p;
                rs += p;
            }
        rs += __shfl_xor(rs, 16);
        rs += __shfl_xor(rs, 32);
        lrow = lrow * alpha + rs;
        mrow = mnew;

        // P^T -> Ps[w][q][kv] (vectorized ushort4 writes)
        #pragma unroll
        for (int c = 0; c < 4; c++) {
            ushort4 pk;
            pk.x = f2b(pv[c][0]); pk.y = f2b(pv[c][1]);
            pk.z = f2b(pv[c][2]); pk.w = f2b(pv[c][3]);
            *(ushort4*)&Ps[w][l15][c * 16 + quad * 4] = pk;
        }

        #pragma unroll
        for (int n = 0; n < 8; n++) oacc[n] *= alpha;

        // O^T = V^T P^T : A = Vs rows, B = Ps rows
        s16x8 pb0 = *(const s16x8*)&Ps[w][l15][quad * 8];
        s16x8 pb1 = *(const s16x8*)&Ps[w][l15][32 + quad * 8];
        #pragma unroll
        for (int mt = 0; mt < 8; mt++) {
            int p0 = quad ^ (l15 & 7);
            int p1 = (4 + quad) ^ (l15 & 7);
            s16x8 va0 = *(const s16x8*)&Vs[mt * 16 + l15][p0 * 8];
            s16x8 va1 = *(const s16x8*)&Vs[mt * 16 + l15][p1 * 8];
            oacc[mt] = __builtin_amdgcn_mfma_f32_16x16x32_bf16(va0, pb0, oacc[mt], 0, 0, 0);
            oacc[mt] = __builtin_amdgcn_mfma_f32_16x16x32_bf16(va1, pb1, oacc[mt], 0, 0, 0);
        }
    }

    // epilogue: O^T[f = mt*16+quad*4+r][q = w*16+l15]
    int grow = b * SQ + q0 + w * 16 + l15;
    u16* Ob = Opart + (size_t)sp * NQ * NF + (size_t)grow * NF;
    #pragma unroll
    for (int mt = 0; mt < 8; mt++) {
        ushort4 ov;
        ov.x = f2b(oacc[mt][0]); ov.y = f2b(oacc[mt][1]);
        ov.z = f2b(oacc[mt][2]); ov.w = f2b(oacc[mt][3]);
        *(ushort4*)(Ob + mt * 16 + quad * 4) = ov;
    }
    if (quad == 0) {
        mpart[sp * NQ + grow] = mrow;
        lpart[sp * NQ + grow] = lrow;
    }
}

// ---------------------------------------------------------------------------
// Kernel 3b: merge SPLIT partials -> x_r fp32
// ---------------------------------------------------------------------------
__global__ __launch_bounds__(256) void attn_merge_kernel(
    const u16* __restrict__ Opart, const float* __restrict__ mpart,
    const float* __restrict__ lpart, float* __restrict__ xr)
{
    int idx = blockIdx.x * 256 + threadIdx.x;
    int row = idx >> 5;
    int c4  = (idx & 31) * 4;
    float m[SPLIT], l[SPLIT];
    #pragma unroll
    for (int s = 0; s < SPLIT; s++) {
        m[s] = mpart[s * NQ + row];
        l[s] = lpart[s * NQ + row];
    }
    float M = m[0];
    #pragma unroll
    for (int s = 1; s < SPLIT; s++) M = fmaxf(M, m[s]);
    float L = 0.f, wgt[SPLIT];
    #pragma unroll
    for (int s = 0; s < SPLIT; s++) {
        wgt[s] = __expf(m[s] - M);
        L += l[s] * wgt[s];
    }
    float o0 = 0.f, o1 = 0.f, o2 = 0.f, o3 = 0.f;
    #pragma unroll
    for (int s = 0; s < SPLIT; s++) {
        ushort4 u = *(const ushort4*)(Opart + (size_t)s * NQ * NF + (size_t)row * NF + c4);
        o0 += wgt[s] * b2f(u.x); o1 += wgt[s] * b2f(u.y);
        o2 += wgt[s] * b2f(u.z); o3 += wgt[s] * b2f(u.w);
    }
    float inv = 1.f / L;
    float4 o = make_float4(o0 * inv, o1 * inv, o2 * inv, o3 * inv);
    *(float4*)(xr + (size_t)row * NF + c4) = o;
}

// ---------------------------------------------------------------------------
// Kernel 4: BN stats
// ---------------------------------------------------------------------------
__global__ __launch_bounds__(256) void bn_stats(
    const float* __restrict__ tbuf, float* __restrict__ stats)
{
    __shared__ float red[8][128];
    __shared__ float redq[8][128];
    const int t     = threadIdx.x;
    const int tf    = t & 31;
    const int trow  = t >> 5;
    const int rbase = blockIdx.x * 128;

    float4 s  = make_float4(0.f, 0.f, 0.f, 0.f);
    float4 sq = make_float4(0.f, 0.f, 0.f, 0.f);
    #pragma unroll 4
    for (int it = 0; it < 16; it++) {
        int r = rbase + trow * 16 + it;
        float4 v = *(const float4*)(tbuf + (size_t)r * NF + tf * 4);
        s.x += v.x; s.y += v.y; s.z += v.z; s.w += v.w;
        sq.x += v.x * v.x; sq.y += v.y * v.y;
        sq.z += v.z * v.z; sq.w += v.w * v.w;
    }
    *(float4*)&red[trow][tf * 4]  = s;
    *(float4*)&redq[trow][tf * 4] = sq;
    __syncthreads();
    if (t < 128) {
        float acc = 0.f;
        #pragma unroll
        for (int i = 0; i < 8; i++) acc += red[i][t];
        atomicAdd(&stats[t], acc);
    } else {
        int f = t - 128;
        float acc = 0.f;
        #pragma unroll
        for (int i = 0; i < 8; i++) acc += redq[i][f];
        atomicAdd(&stats[128 + f], acc);
    }
}

// ---------------------------------------------------------------------------
// Kernel 5: out = x_dec + BN(t)
// ---------------------------------------------------------------------------
__global__ __launch_bounds__(256) void bn_finalize(
    const float* __restrict__ tbuf, const float* __restrict__ xdec,
    const float* __restrict__ stats, const float* __restrict__ gamma,
    const float* __restrict__ beta, float* __restrict__ out)
{
    const int g = blockIdx.x * 256 + threadIdx.x;
    const int e = g * 4;
    const int f = e & (NF - 1);
    const float invN = 1.0f / (float)NQ;
    float4 tv = *(const float4*)(tbuf + e);
    float4 xv = *(const float4*)(xdec + e);
    float o[4], tt[4] = {tv.x, tv.y, tv.z, tv.w}, xx[4] = {xv.x, xv.y, xv.z, xv.w};
    #pragma unroll
    for (int u = 0; u < 4; u++) {
        float sum  = stats[f + u];
        float sumq = stats[128 + f + u];
        float mean = sum * invN;
        float var  = sumq * invN - mean * mean;
        float sc   = rsqrtf(var + BN_EPS) * gamma[f + u];
        o[u] = xx[u] + (tt[u] - mean) * sc + beta[f + u];
    }
    float4 ov = make_float4(o[0], o[1], o[2], o[3]);
    *(float4*)(out + e) = ov;
}

// ---------------------------------------------------------------------------
extern "C" void kernel_launch(void* const* d_in, const int* in_sizes, int n_in,
                              void* d_out, int out_size, void* d_ws, size_t ws_size,
                              hipStream_t stream) {
    const float* xdec_feat = (const float*)d_in[0];
    const float* xenc_feat = (const float*)d_in[1];
    const int*   nbr       = (const int*)d_in[2];
    const float* Wp1       = (const float*)d_in[3];
    const float* Wq        = (const float*)d_in[4];
    const float* Wk        = (const float*)d_in[5];
    const float* Wv        = (const float*)d_in[6];
    const float* Wt        = (const float*)d_in[7];
    const float* gamma     = (const float*)d_in[8];
    const float* beta      = (const float*)d_in[9];
    float* out = (float*)d_out;

    char* wsb = (char*)d_ws;
    const size_t MB = 1024 * 1024;
    float* xdec  = (float*)(wsb + 0);             //  0..8M   fp32 NQ*NF
    u16*   qbuf  = (u16*)  (wsb + 8 * MB);        //  8..12M  bf16 NQ*NF
    u16*   kbuf  = (u16*)  (wsb + 12 * MB);       // 12..20M  bf16 NKV*NF
    u16*   vt    = (u16*)  (wsb + 20 * MB);       // 20..28M  bf16 NKV*NF (V^T per batch)
    u16*   opart = (u16*)  (wsb + 28 * MB);       // 28..44M  bf16 SPLIT*NQ*NF
    u16*   xf_bf = (u16*)  (wsb + 28 * MB);       // reuse: dead before attn writes opart
    u16*   wp1t  = (u16*)  (wsb + 31 * MB);       // 27*128*64 bf16 (~0.45M)
    float* mpart = (float*)(wsb + 44 * MB);
    float* lpart = (float*)(wsb + 44 * MB + 256 * 1024);
    float* stats = (float*)(wsb + 44 * MB + 512 * 1024);
    float* xr    = (float*)(wsb + 20 * MB);       // reuses vt (dead after attn)
    float* tbuf  = (float*)(wsb + 8 * MB);        // reuses qbuf+kbuf

    hipMemsetAsync(stats, 0, 256 * sizeof(float), stream);

    cvt_bf16_kernel<<<(NQ * CIN) / 1024, 256, 0, stream>>>(xdec_feat, xf_bf);
    cvt_wp1t_kernel<<<(NOFF * NF * 16) / 256, 256, 0, stream>>>(Wp1, wp1t);
    p1conv_mfma_kernel<<<dim3(NQ / 64, 2), 256, 0, stream>>>(xf_bf, nbr, wp1t, xdec);
    gemm_nf128<1><<<NQ / 64, 256, 0, stream>>>(xdec, Wq, (void*)qbuf, NF);
    gemm_nf128<1><<<NKV / 64, 256, 0, stream>>>(xenc_feat, Wk, (void*)kbuf, CIN);
    gemm_nf128<2><<<NKV / 64, 256, 0, stream>>>(xenc_feat, Wv, (void*)vt, CIN);
    attn_mfma_kernel<<<dim3(SQ / 64, BATCH, SPLIT), 256, 0, stream>>>(
        qbuf, kbuf, vt, opart, mpart, lpart);
    attn_merge_kernel<<<(NQ * 32) / 256, 256, 0, stream>>>(opart, mpart, lpart, xr);
    gemm_nf128<0><<<NQ / 64, 256, 0, stream>>>(xr, Wt, (void*)tbuf, NF);
    bn_stats<<<NQ / 128, 256, 0, stream>>>(tbuf, stats);
    bn_finalize<<<(NQ * NF) / 1024, 256, 0, stream>>>(tbuf, xdec, stats, gamma, beta, out);
}

// Round 4
// 214.916 us; speedup vs baseline: 4.7652x; 1.0591x over previous
//
#include <hip/hip_runtime.h>
#include <math.h>

#define NQ      16384
#define NKV     32768
#define CIN     64
#define NF      128
#define NOFF    27
#define BATCH   8
#define SQ      2048
#define SKV     4096
#define BN_EPS  1e-4f
#define SPLIT   4
#define KV_PER_SPLIT (SKV / SPLIT)           // 1024
#define TILES_PER_SPLIT (KV_PER_SPLIT / 64)  // 16

typedef unsigned short u16;
typedef __attribute__((ext_vector_type(4))) float f32x4;
typedef __attribute__((ext_vector_type(8))) short s16x8;

__device__ __forceinline__ u16 f2b(float x) {
    union { float f; unsigned u; } c; c.f = x;
    unsigned r = (c.u + 0x7FFFu + ((c.u >> 16) & 1u)) >> 16;
    return (u16)r;
}
__device__ __forceinline__ float b2f(u16 x) {
    union { unsigned u; float f; } c; c.u = ((unsigned)x) << 16;
    return c.f;
}
// async global->LDS, 16B per lane; dest = wave-uniform base + lane*16
__device__ __forceinline__ void g2l16(const void* gp, void* lp) {
    __builtin_amdgcn_global_load_lds(
        (const __attribute__((address_space(1))) unsigned*)gp,
        (__attribute__((address_space(3))) unsigned*)lp, 16, 0, 0);
}

// ---------------------------------------------------------------------------
// cvt: fp32 -> bf16 flat (n multiple of 1024)
// ---------------------------------------------------------------------------
__global__ __launch_bounds__(256) void cvt_bf16_kernel(
    const float* __restrict__ src, u16* __restrict__ dst)
{
    int i = (blockIdx.x * 256 + threadIdx.x) * 4;
    float4 v = *(const float4*)(src + i);
    ushort4 o;
    o.x = f2b(v.x); o.y = f2b(v.y); o.z = f2b(v.z); o.w = f2b(v.w);
    *(ushort4*)(dst + i) = o;
}

// ---------------------------------------------------------------------------
// cvt Wp1[27][64][128] fp32 -> wp1t[27][128][64] bf16 (transposed)
// ---------------------------------------------------------------------------
__global__ __launch_bounds__(256) void cvt_wp1t_kernel(
    const float* __restrict__ src, u16* __restrict__ dst)
{
    int id = blockIdx.x * 256 + threadIdx.x;      // 27*128*16 = 55296
    int ko = id >> 11;
    int r  = id & 2047;
    int f  = r >> 4;
    int c4 = (r & 15) * 4;
    const float* s = src + (size_t)ko * 8192 + (size_t)c4 * NF + f;
    ushort4 o;
    o.x = f2b(s[0]); o.y = f2b(s[NF]); o.z = f2b(s[2 * NF]); o.w = f2b(s[3 * NF]);
    *(ushort4*)(dst + (size_t)ko * 8192 + (size_t)f * 64 + c4) = o;
}

// ---------------------------------------------------------------------------
// cvt all 4 attention/proj weights W[K][128] fp32 -> WT[128][K] bf16.
// Wq(K=128): ids 0..4095, Wk(64): 4096..6143, Wv(64): 6144..8191, Wt(128): 8192..12287
// grid = 48 x 256
// ---------------------------------------------------------------------------
__device__ __forceinline__ void wtrans_one(
    const float* __restrict__ src, u16* __restrict__ dst, int K, int id)
{
    int n  = id / (K / 4);
    int k4 = (id % (K / 4)) * 4;
    const float* s = src + (size_t)k4 * NF + n;
    ushort4 o;
    o.x = f2b(s[0]); o.y = f2b(s[NF]); o.z = f2b(s[2 * NF]); o.w = f2b(s[3 * NF]);
    *(ushort4*)(dst + (size_t)n * K + k4) = o;
}

__global__ __launch_bounds__(256) void cvt_weights_kernel(
    const float* __restrict__ Wq, const float* __restrict__ Wk,
    const float* __restrict__ Wv, const float* __restrict__ Wt,
    u16* __restrict__ wqT, u16* __restrict__ wkT,
    u16* __restrict__ wvT, u16* __restrict__ wtT)
{
    int id = blockIdx.x * 256 + threadIdx.x;
    if (id < 4096)        wtrans_one(Wq, wqT, 128, id);
    else if (id < 6144)   wtrans_one(Wk, wkT, 64, id - 4096);
    else if (id < 8192)   wtrans_one(Wv, wvT, 64, id - 6144);
    else                  wtrans_one(Wt, wtT, 128, id - 8192);
}

// ---------------------------------------------------------------------------
// Kernel 1: p1 conv via MFMA. grid = (NQ/64, 2), block 256.
// Emits fp32 xdec AND bf16 xdec copy (for the q-GEMM).
// ---------------------------------------------------------------------------
__global__ __launch_bounds__(256, 3) void p1conv_mfma_kernel(
    const u16* __restrict__ xf, const int* __restrict__ nbr,
    const u16* __restrict__ wt, float* __restrict__ out,
    u16* __restrict__ outb)
{
    __shared__ u16 As[64][64];      // [pt][c] phys chunk = k8 ^ (row&7)
    __shared__ u16 Bs[64][64];      // [f][c]  phys chunk = k8 ^ (row&7)
    __shared__ int nbr_s[64][28];

    const int t    = threadIdx.x;
    const int w    = t >> 6;
    const int lane = t & 63;
    const int quad = lane >> 4;
    const int l15  = lane & 15;
    const int base = blockIdx.x * 64;
    const int fh   = blockIdx.y;

    for (int i = t; i < 64 * NOFF; i += 256)
        nbr_s[i / NOFF][i % NOFF] = nbr[(size_t)base * NOFF + i];

    f32x4 oacc[4];
    #pragma unroll
    for (int n = 0; n < 4; n++) oacc[n] = (f32x4)0.f;

    __syncthreads();   // nbr_s ready

    for (int ko = 0; ko < NOFF; ko++) {
        if (ko) __syncthreads();
        #pragma unroll
        for (int c = 0; c < 2; c++) {
            int row = w * 16 + c * 8 + (lane >> 3);
            int k8  = (lane & 7) ^ (row & 7);
            int nb  = nbr_s[row][ko];
            g2l16(xf + (size_t)nb * CIN + k8 * 8, &As[w * 16 + c * 8][0]);
        }
        #pragma unroll
        for (int c = 0; c < 2; c++) {
            int row = w * 16 + c * 8 + (lane >> 3);
            int k8  = (lane & 7) ^ (row & 7);
            g2l16(wt + (size_t)ko * 8192 + (size_t)(fh * 64 + row) * 64 + k8 * 8,
                  &Bs[w * 16 + c * 8][0]);
        }
        __syncthreads();

        s16x8 af[2];
        #pragma unroll
        for (int ks = 0; ks < 2; ks++) {
            int p = (ks * 4 + quad) ^ (l15 & 7);
            af[ks] = *(const s16x8*)&As[w * 16 + l15][p * 8];
        }
        #pragma unroll
        for (int nt = 0; nt < 4; nt++) {
            #pragma unroll
            for (int ks = 0; ks < 2; ks++) {
                int p = (ks * 4 + quad) ^ (l15 & 7);
                s16x8 bf = *(const s16x8*)&Bs[nt * 16 + l15][p * 8];
                oacc[nt] = __builtin_amdgcn_mfma_f32_16x16x32_bf16(af[ks], bf, oacc[nt], 0, 0, 0);
            }
        }
    }
    #pragma unroll
    for (int nt = 0; nt < 4; nt++)
        #pragma unroll
        for (int r = 0; r < 4; r++) {
            size_t idx = (size_t)(base + w * 16 + quad * 4 + r) * NF + fh * 64 + nt * 16 + l15;
            out[idx]  = oacc[nt][r];
            outb[idx] = f2b(oacc[nt][r]);
        }
}

// ---------------------------------------------------------------------------
// Kernel 2: MFMA GEMM, no LDS. C[M,128] = A[M,K] @ W[K,128], A bf16 row-major,
// WT bf16 [n][k] (B-operand layout). MODE 0: fp32 out; 1: bf16 out; 2: bf16 V^T.
// grid = M/64, block 256 (4 waves x 16 rows).
// ---------------------------------------------------------------------------
template<int MODE, int K>
__global__ __launch_bounds__(256) void gemm_mfma(
    const u16* __restrict__ A, const u16* __restrict__ WT,
    void* __restrict__ out)
{
    const int t    = threadIdx.x;
    const int w    = t >> 6;
    const int lane = t & 63;
    const int quad = lane >> 4;
    const int l15  = lane & 15;
    const int m0   = blockIdx.x * 64 + w * 16;
    constexpr int KF = K / 32;

    s16x8 af[KF];
    const u16* Ap = A + (size_t)(m0 + l15) * K + quad * 8;
    #pragma unroll
    for (int ks = 0; ks < KF; ks++) af[ks] = *(const s16x8*)(Ap + ks * 32);

    f32x4 oacc[8];
    #pragma unroll
    for (int nt = 0; nt < 8; nt++) {
        oacc[nt] = (f32x4)0.f;
        const u16* Wp = WT + (size_t)(nt * 16 + l15) * K + quad * 8;
        #pragma unroll
        for (int ks = 0; ks < KF; ks++) {
            s16x8 bf = *(const s16x8*)(Wp + ks * 32);
            oacc[nt] = __builtin_amdgcn_mfma_f32_16x16x32_bf16(af[ks], bf, oacc[nt], 0, 0, 0);
        }
    }

    if (MODE == 0) {
        float* C = (float*)out;
        #pragma unroll
        for (int nt = 0; nt < 8; nt++)
            #pragma unroll
            for (int r = 0; r < 4; r++)
                C[(size_t)(m0 + quad * 4 + r) * NF + nt * 16 + l15] = oacc[nt][r];
    } else if (MODE == 1) {
        u16* C = (u16*)out;
        #pragma unroll
        for (int nt = 0; nt < 8; nt++)
            #pragma unroll
            for (int r = 0; r < 4; r++)
                C[(size_t)(m0 + quad * 4 + r) * NF + nt * 16 + l15] = f2b(oacc[nt][r]);
    } else {
        // V^T: [b][f][kv]; rows m -> (bb, kv); r=0..3 are consecutive kv
        u16* C = (u16*)out;
        int m  = m0 + quad * 4;
        int bb = m >> 12;
        int kv = m & 4095;
        #pragma unroll
        for (int nt = 0; nt < 8; nt++) {
            ushort4 pk;
            pk.x = f2b(oacc[nt][0]); pk.y = f2b(oacc[nt][1]);
            pk.z = f2b(oacc[nt][2]); pk.w = f2b(oacc[nt][3]);
            *(ushort4*)(C + (size_t)(bb * NF + nt * 16 + l15) * SKV + kv) = pk;
        }
    }
}

// ---------------------------------------------------------------------------
// Kernel 3: MFMA flash attention (swapped-operand form). Unchanged from R3.
// ---------------------------------------------------------------------------
__global__ __launch_bounds__(256, 3) void attn_mfma_kernel(
    const u16* __restrict__ Q, const u16* __restrict__ K,
    const u16* __restrict__ Vt, u16* __restrict__ Opart,
    float* __restrict__ mpart, float* __restrict__ lpart)
{
    __shared__ u16 Ks[64][128];     // [kv][f]  phys chunk = k8 ^ (row&15)
    __shared__ u16 Vs[128][64];     // [f][kv]  phys chunk = k8 ^ (row&7)
    __shared__ u16 Ps[4][16][72];   // [wave][q][kv]

    const int t    = threadIdx.x;
    const int b    = blockIdx.y;
    const int q0   = blockIdx.x * 64;
    const int sp   = blockIdx.z;
    const int w    = t >> 6;
    const int lane = t & 63;
    const int quad = lane >> 4;
    const int l15  = lane & 15;

    const u16* Kb  = K  + (size_t)b * SKV * NF;
    const u16* Vtb = Vt + (size_t)b * NF * SKV;

    const u16* Qp = Q + ((size_t)(b * SQ + q0 + w * 16 + l15)) * NF + quad * 8;
    s16x8 qf[4];
    #pragma unroll
    for (int ks = 0; ks < 4; ks++) qf[ks] = *(const s16x8*)(Qp + ks * 32);

    f32x4 oacc[8];
    #pragma unroll
    for (int n = 0; n < 8; n++) oacc[n] = (f32x4)0.f;
    float mrow = -1e30f, lrow = 0.f;

    const int kvbase = sp * KV_PER_SPLIT;

    for (int tile = 0; tile < TILES_PER_SPLIT; tile++) {
        int kv0 = kvbase + tile * 64;
        __syncthreads();
        #pragma unroll
        for (int c = 0; c < 4; c++) {
            int row = w * 16 + c * 4 + (lane >> 4);
            int k8  = (lane & 15) ^ (row & 15);
            g2l16(Kb + (size_t)(kv0 + row) * NF + k8 * 8, &Ks[w * 16 + c * 4][0]);
        }
        #pragma unroll
        for (int c = 0; c < 4; c++) {
            int row = w * 32 + c * 8 + (lane >> 3);
            int k8  = (lane & 7) ^ (row & 7);
            g2l16(Vtb + (size_t)row * SKV + kv0 + k8 * 8, &Vs[w * 32 + c * 8][0]);
        }
        __syncthreads();

        f32x4 sacc[4];
        #pragma unroll
        for (int c = 0; c < 4; c++) {
            sacc[c] = (f32x4)0.f;
            #pragma unroll
            for (int ks = 0; ks < 4; ks++) {
                int p = (ks * 4 + quad) ^ l15;
                s16x8 ka = *(const s16x8*)&Ks[c * 16 + l15][p * 8];
                sacc[c] = __builtin_amdgcn_mfma_f32_16x16x32_bf16(ka, qf[ks], sacc[c], 0, 0, 0);
            }
        }

        float mx = sacc[0][0];
        #pragma unroll
        for (int c = 0; c < 4; c++)
            #pragma unroll
            for (int r = 0; r < 4; r++) mx = fmaxf(mx, sacc[c][r]);
        mx = fmaxf(mx, __shfl_xor(mx, 16));
        mx = fmaxf(mx, __shfl_xor(mx, 32));
        float mnew  = fmaxf(mrow, mx);
        float alpha = __expf(mrow - mnew);
        float pv[4][4];
        float rs = 0.f;
        #pragma unroll
        for (int c = 0; c < 4; c++)
            #pragma unroll
            for (int r = 0; r < 4; r++) {
                float p = __expf(sacc[c][r] - mnew);
                pv[c][r] = p;
                rs += p;
            }
        rs += __shfl_xor(rs, 16);
        rs += __shfl_xor(rs, 32);
        lrow = lrow * alpha + rs;
        mrow = mnew;

        #pragma unroll
        for (int c = 0; c < 4; c++) {
            ushort4 pk;
            pk.x = f2b(pv[c][0]); pk.y = f2b(pv[c][1]);
            pk.z = f2b(pv[c][2]); pk.w = f2b(pv[c][3]);
            *(ushort4*)&Ps[w][l15][c * 16 + quad * 4] = pk;
        }

        #pragma unroll
        for (int n = 0; n < 8; n++) oacc[n] *= alpha;

        s16x8 pb0 = *(const s16x8*)&Ps[w][l15][quad * 8];
        s16x8 pb1 = *(const s16x8*)&Ps[w][l15][32 + quad * 8];
        #pragma unroll
        for (int mt = 0; mt < 8; mt++) {
            int p0 = quad ^ (l15 & 7);
            int p1 = (4 + quad) ^ (l15 & 7);
            s16x8 va0 = *(const s16x8*)&Vs[mt * 16 + l15][p0 * 8];
            s16x8 va1 = *(const s16x8*)&Vs[mt * 16 + l15][p1 * 8];
            oacc[mt] = __builtin_amdgcn_mfma_f32_16x16x32_bf16(va0, pb0, oacc[mt], 0, 0, 0);
            oacc[mt] = __builtin_amdgcn_mfma_f32_16x16x32_bf16(va1, pb1, oacc[mt], 0, 0, 0);
        }
    }

    int grow = b * SQ + q0 + w * 16 + l15;
    u16* Ob = Opart + (size_t)sp * NQ * NF + (size_t)grow * NF;
    #pragma unroll
    for (int mt = 0; mt < 8; mt++) {
        ushort4 ov;
        ov.x = f2b(oacc[mt][0]); ov.y = f2b(oacc[mt][1]);
        ov.z = f2b(oacc[mt][2]); ov.w = f2b(oacc[mt][3]);
        *(ushort4*)(Ob + mt * 16 + quad * 4) = ov;
    }
    if (quad == 0) {
        mpart[sp * NQ + grow] = mrow;
        lpart[sp * NQ + grow] = lrow;
    }
}

// ---------------------------------------------------------------------------
// Kernel 3b: merge SPLIT partials -> x_r bf16 (feeds t-GEMM)
// ---------------------------------------------------------------------------
__global__ __launch_bounds__(256) void attn_merge_kernel(
    const u16* __restrict__ Opart, const float* __restrict__ mpart,
    const float* __restrict__ lpart, u16* __restrict__ xrb)
{
    int idx = blockIdx.x * 256 + threadIdx.x;
    int row = idx >> 5;
    int c4  = (idx & 31) * 4;
    float m[SPLIT], l[SPLIT];
    #pragma unroll
    for (int s = 0; s < SPLIT; s++) {
        m[s] = mpart[s * NQ + row];
        l[s] = lpart[s * NQ + row];
    }
    float M = m[0];
    #pragma unroll
    for (int s = 1; s < SPLIT; s++) M = fmaxf(M, m[s]);
    float L = 0.f, wgt[SPLIT];
    #pragma unroll
    for (int s = 0; s < SPLIT; s++) {
        wgt[s] = __expf(m[s] - M);
        L += l[s] * wgt[s];
    }
    float o0 = 0.f, o1 = 0.f, o2 = 0.f, o3 = 0.f;
    #pragma unroll
    for (int s = 0; s < SPLIT; s++) {
        ushort4 u = *(const ushort4*)(Opart + (size_t)s * NQ * NF + (size_t)row * NF + c4);
        o0 += wgt[s] * b2f(u.x); o1 += wgt[s] * b2f(u.y);
        o2 += wgt[s] * b2f(u.z); o3 += wgt[s] * b2f(u.w);
    }
    float inv = 1.f / L;
    ushort4 ob;
    ob.x = f2b(o0 * inv); ob.y = f2b(o1 * inv);
    ob.z = f2b(o2 * inv); ob.w = f2b(o3 * inv);
    *(ushort4*)(xrb + (size_t)row * NF + c4) = ob;
}

// ---------------------------------------------------------------------------
// Kernel 4: BN stats
// ---------------------------------------------------------------------------
__global__ __launch_bounds__(256) void bn_stats(
    const float* __restrict__ tbuf, float* __restrict__ stats)
{
    __shared__ float red[8][128];
    __shared__ float redq[8][128];
    const int t     = threadIdx.x;
    const int tf    = t & 31;
    const int trow  = t >> 5;
    const int rbase = blockIdx.x * 128;

    float4 s  = make_float4(0.f, 0.f, 0.f, 0.f);
    float4 sq = make_float4(0.f, 0.f, 0.f, 0.f);
    #pragma unroll 4
    for (int it = 0; it < 16; it++) {
        int r = rbase + trow * 16 + it;
        float4 v = *(const float4*)(tbuf + (size_t)r * NF + tf * 4);
        s.x += v.x; s.y += v.y; s.z += v.z; s.w += v.w;
        sq.x += v.x * v.x; sq.y += v.y * v.y;
        sq.z += v.z * v.z; sq.w += v.w * v.w;
    }
    *(float4*)&red[trow][tf * 4]  = s;
    *(float4*)&redq[trow][tf * 4] = sq;
    __syncthreads();
    if (t < 128) {
        float acc = 0.f;
        #pragma unroll
        for (int i = 0; i < 8; i++) acc += red[i][t];
        atomicAdd(&stats[t], acc);
    } else {
        int f = t - 128;
        float acc = 0.f;
        #pragma unroll
        for (int i = 0; i < 8; i++) acc += redq[i][f];
        atomicAdd(&stats[128 + f], acc);
    }
}

// ---------------------------------------------------------------------------
// Kernel 5: out = x_dec + BN(t)
// ---------------------------------------------------------------------------
__global__ __launch_bounds__(256) void bn_finalize(
    const float* __restrict__ tbuf, const float* __restrict__ xdec,
    const float* __restrict__ stats, const float* __restrict__ gamma,
    const float* __restrict__ beta, float* __restrict__ out)
{
    const int g = blockIdx.x * 256 + threadIdx.x;
    const int e = g * 4;
    const int f = e & (NF - 1);
    const float invN = 1.0f / (float)NQ;
    float4 tv = *(const float4*)(tbuf + e);
    float4 xv = *(const float4*)(xdec + e);
    float o[4], tt[4] = {tv.x, tv.y, tv.z, tv.w}, xx[4] = {xv.x, xv.y, xv.z, xv.w};
    #pragma unroll
    for (int u = 0; u < 4; u++) {
        float sum  = stats[f + u];
        float sumq = stats[128 + f + u];
        float mean = sum * invN;
        float var  = sumq * invN - mean * mean;
        float sc   = rsqrtf(var + BN_EPS) * gamma[f + u];
        o[u] = xx[u] + (tt[u] - mean) * sc + beta[f + u];
    }
    float4 ov = make_float4(o[0], o[1], o[2], o[3]);
    *(float4*)(out + e) = ov;
}

// ---------------------------------------------------------------------------
extern "C" void kernel_launch(void* const* d_in, const int* in_sizes, int n_in,
                              void* d_out, int out_size, void* d_ws, size_t ws_size,
                              hipStream_t stream) {
    const float* xdec_feat = (const float*)d_in[0];
    const float* xenc_feat = (const float*)d_in[1];
    const int*   nbr       = (const int*)d_in[2];
    const float* Wp1       = (const float*)d_in[3];
    const float* Wq        = (const float*)d_in[4];
    const float* Wk        = (const float*)d_in[5];
    const float* Wv        = (const float*)d_in[6];
    const float* Wt        = (const float*)d_in[7];
    const float* gamma     = (const float*)d_in[8];
    const float* beta      = (const float*)d_in[9];
    float* out = (float*)d_out;

    char* wsb = (char*)d_ws;
    const size_t MB = 1024 * 1024;
    float* xdec   = (float*)(wsb + 0);            //  0..8M   fp32 NQ*NF
    u16*   qbuf   = (u16*)  (wsb + 8 * MB);       //  8..12M  bf16 NQ*NF
    u16*   kbuf   = (u16*)  (wsb + 12 * MB);      // 12..20M  bf16 NKV*NF
    u16*   vt     = (u16*)  (wsb + 20 * MB);      // 20..28M  bf16 NKV*NF (V^T)
    u16*   opart  = (u16*)  (wsb + 28 * MB);      // 28..44M  bf16 SPLIT*NQ*NF
    u16*   xf_bf  = (u16*)  (wsb + 28 * MB);      // 2M, dead before attn
    u16*   xenc_b = (u16*)  (wsb + 30 * MB);      // 4M, dead before attn
    u16*   xdec_b = (u16*)  (wsb + 34 * MB);      // 4M, dead before attn
    u16*   wp1t   = (u16*)  (wsb + 44 * MB);      // ~432K
    u16*   wqT    = (u16*)  (wsb + 44 * MB + 512 * 1024);        // 32K
    u16*   wkT    = (u16*)  (wsb + 44 * MB + 512 * 1024 + 32768);  // 16K
    u16*   wvT    = (u16*)  (wsb + 44 * MB + 512 * 1024 + 49152);  // 16K
    u16*   wtT    = (u16*)  (wsb + 44 * MB + 512 * 1024 + 65536);  // 32K
    float* mpart  = (float*)(wsb + 45 * MB);
    float* lpart  = (float*)(wsb + 45 * MB + 256 * 1024);
    float* stats  = (float*)(wsb + 45 * MB + 512 * 1024);
    u16*   xr_bf  = (u16*)  (wsb + 20 * MB);      // reuses vt (dead after attn)
    float* tbuf   = (float*)(wsb + 8 * MB);       // reuses qbuf+kbuf

    hipMemsetAsync(stats, 0, 256 * sizeof(float), stream);

    cvt_bf16_kernel<<<(NQ * CIN) / 1024, 256, 0, stream>>>(xdec_feat, xf_bf);
    cvt_bf16_kernel<<<(NKV * CIN) / 1024, 256, 0, stream>>>(xenc_feat, xenc_b);
    cvt_wp1t_kernel<<<(NOFF * NF * 16) / 256, 256, 0, stream>>>(Wp1, wp1t);
    cvt_weights_kernel<<<48, 256, 0, stream>>>(Wq, Wk, Wv, Wt, wqT, wkT, wvT, wtT);
    p1conv_mfma_kernel<<<dim3(NQ / 64, 2), 256, 0, stream>>>(xf_bf, nbr, wp1t, xdec, xdec_b);
    gemm_mfma<1, 128><<<NQ / 64, 256, 0, stream>>>(xdec_b, wqT, (void*)qbuf);
    gemm_mfma<1, 64><<<NKV / 64, 256, 0, stream>>>(xenc_b, wkT, (void*)kbuf);
    gemm_mfma<2, 64><<<NKV / 64, 256, 0, stream>>>(xenc_b, wvT, (void*)vt);
    attn_mfma_kernel<<<dim3(SQ / 64, BATCH, SPLIT), 256, 0, stream>>>(
        qbuf, kbuf, vt, opart, mpart, lpart);
    attn_merge_kernel<<<(NQ * 32) / 256, 256, 0, stream>>>(opart, mpart, lpart, xr_bf);
    gemm_mfma<0, 128><<<NQ / 64, 256, 0, stream>>>(xr_bf, wtT, (void*)tbuf);
    bn_stats<<<NQ / 128, 256, 0, stream>>>(tbuf, stats);
    bn_finalize<<<(NQ * NF) / 1024, 256, 0, stream>>>(tbuf, xdec, stats, gamma, beta, out);
}